// Round 17
// baseline (91.953 us; speedup 1.0000x reference)
//
#include <hip/hip_runtime.h>

typedef __attribute__((ext_vector_type(8))) short short8;
typedef __attribute__((ext_vector_type(4))) short short4v;
typedef __attribute__((ext_vector_type(4))) float f32x4;
typedef __attribute__((ext_vector_type(2))) unsigned int uint2v;

constexpr int SL = 2048, BS = 4, D = 512, H = 8, NH = 64;
constexpr int M_ROWS = SL * BS;   // 8192
constexpr float SCALE = 0.125f;   // 1/sqrt(64)
constexpr float LOG2E = 1.44269504088896340736f;

__device__ __forceinline__ unsigned short f2bf(float f) {
  union { float f; unsigned u; } v; v.f = f;
  unsigned r = v.u + 0x7FFFu + ((v.u >> 16) & 1u);
  return (unsigned short)(r >> 16);
}

__device__ __forceinline__ unsigned cvt_pk_bf16(float a, float b) {
  unsigned r;
  asm("v_cvt_pk_bf16_f32 %0, %1, %2" : "=v"(r) : "v"(a), "v"(b));
  return r;
}

__device__ __forceinline__ float fast_exp2(float x) {
  float r;
  asm("v_exp_f32 %0, %1" : "=v"(r) : "v"(x));
  return r;
}

// async global->LDS, 16B per lane; LDS dest = wave-uniform base + lane*16
__device__ __forceinline__ void gl16(const void* g, void* l) {
  __builtin_amdgcn_global_load_lds(
      (const __attribute__((address_space(1))) unsigned int*)g,
      (__attribute__((address_space(3))) unsigned int*)l, 16, 0, 0);
}

// ---------------------------------------------------------------------------
// conv3: stream-convert the three f32 inputs to bf16 (one pass, ~72 MB).
// x -> d0 (d_out scratch), kx -> d1 (qb), vx -> d2 (kb).
// ---------------------------------------------------------------------------
__global__ __launch_bounds__(256) void conv3(
    const float* __restrict__ x0, const float* __restrict__ x1,
    const float* __restrict__ x2,
    unsigned short* __restrict__ d0, unsigned short* __restrict__ d1,
    unsigned short* __restrict__ d2) {
  const int u = blockIdx.x * 256 + threadIdx.x;   // 524288 units of 8 elems
#pragma unroll
  for (int z = 0; z < 3; ++z) {
    const float* src = z == 0 ? x0 : (z == 1 ? x1 : x2);
    unsigned short* dst = z == 0 ? d0 : (z == 1 ? d1 : d2);
    f32x4 v0 = *reinterpret_cast<const f32x4*>(&src[(size_t)u * 8]);
    f32x4 v1 = *reinterpret_cast<const f32x4*>(&src[(size_t)u * 8 + 4]);
    union { unsigned uu[4]; short8 s; } pk;
    pk.uu[0] = cvt_pk_bf16(v0[0], v0[1]);
    pk.uu[1] = cvt_pk_bf16(v0[2], v0[3]);
    pk.uu[2] = cvt_pk_bf16(v1[0], v1[1]);
    pk.uu[3] = cvt_pk_bf16(v1[2], v1[3]);
    *reinterpret_cast<short8*>(&dst[(size_t)u * 8]) = pk.s;
  }
}

// ---------------------------------------------------------------------------
// prep: W[512][512] f32 row-major -> W^T[n][k] bf16, LDS-tiled 64x64.
// ---------------------------------------------------------------------------
__global__ __launch_bounds__(256) void prep_wt(
    const float* __restrict__ w0, const float* __restrict__ w1,
    const float* __restrict__ w2, const float* __restrict__ w3,
    unsigned short* __restrict__ wtb) {
  __shared__ float tl[64][65];
  const int tid = threadIdx.x;
  const int wi = blockIdx.x >> 6, t6 = blockIdx.x & 63;
  const int k0 = (t6 >> 3) * 64, n0 = (t6 & 7) * 64;
  const float* W = wi == 0 ? w0 : (wi == 1 ? w1 : (wi == 2 ? w2 : w3));
  unsigned short* WT = wtb + (size_t)wi * D * D;

#pragma unroll
  for (int i = 0; i < 4; ++i) {
    int k = (tid >> 4) + i * 16, n4 = (tid & 15) * 4;
    f32x4 v = *reinterpret_cast<const f32x4*>(&W[(size_t)(k0 + k) * D + n0 + n4]);
#pragma unroll
    for (int j = 0; j < 4; ++j) tl[n4 + j][k] = v[j];
  }
  __syncthreads();
#pragma unroll
  for (int i = 0; i < 2; ++i) {
    int n = (tid >> 3) + i * 32, k8 = (tid & 7) * 8;
    union { unsigned u[4]; short8 s; } pk;
#pragma unroll
    for (int j = 0; j < 4; ++j)
      pk.u[j] = cvt_pk_bf16(tl[n][k8 + 2 * j], tl[n][k8 + 2 * j + 1]);
    *reinterpret_cast<short8*>(&WT[(size_t)(n0 + n) * D + k0 + k8]) = pk.s;
  }
}

// ---------------------------------------------------------------------------
// GEMM (all-bf16): tile 128x64, 4 waves, tri-buffered gl16 staging for A and
// B, staged two tiles ahead, counted closing vmcnt(6) (never drained to 0
// mid-loop). No cvt / ds_write / lgkm in the main loop. LDS 72 KB.
// OUT_MODE: 0 f32 row-major, 1 bf16 row-major, 2 bf16 V^T [b][h][nh][s] with
// per-64-key sigma permutation (flash depends on it).
// ---------------------------------------------------------------------------
template <int OUT_MODE>
__global__ __launch_bounds__(256) void gemm_bf16(
    const unsigned short* __restrict__ Abf,
    const unsigned short* __restrict__ BT,
    const float* __restrict__ bias, void* __restrict__ Outp, float scale) {
  __shared__ __align__(16) unsigned short smem[3 * 8192 + 3 * 4096];  // 72 KB
  const int tid = threadIdx.x;
  const int brow = blockIdx.x * 128;
  const int bcol = blockIdx.y * 64;
  const int lane = tid & 63;
  const int wid = tid >> 6;
  const int wr = (wid >> 1) * 64;   // 2 wave rows of 64
  const int wc = (wid & 1) * 32;    // 2 wave cols of 32
  const int r = lane & 15;
  const int g = lane >> 4;

  auto a_buf = [&](int b) { return smem + b * 8192; };
  auto b_buf = [&](int b) { return smem + 3 * 8192 + b * 4096; };

  f32x4 acc[4][2];
#pragma unroll
  for (int m = 0; m < 4; ++m)
#pragma unroll
    for (int n = 0; n < 2; ++n) acc[m][n] = f32x4{0.f, 0.f, 0.f, 0.f};

  auto STAGE_A = [&](int kt, int bsel) {
    unsigned short* al = a_buf(bsel);
#pragma unroll
    for (int j = 0; j < 4; ++j) {
      int c = j * 256 + tid;
      int row = c >> 3, c8 = (c & 7) ^ (row & 7);
      gl16(&Abf[(size_t)(brow + row) * D + kt + c8 * 8], &al[c * 8]);
    }
  };
  auto STAGE_B = [&](int kt, int bsel) {
    unsigned short* bl = b_buf(bsel);
#pragma unroll
    for (int j = 0; j < 2; ++j) {
      int c = j * 256 + tid;
      int row = c >> 3, c8 = (c & 7) ^ (row & 7);
      gl16(&BT[(size_t)(bcol + row) * D + kt + c8 * 8], &bl[c * 8]);
    }
  };
  auto COMPUTE = [&](int bsel) {
    const unsigned short* al = a_buf(bsel);
    const unsigned short* bl = b_buf(bsel);
#pragma unroll
    for (int kk2 = 0; kk2 < 2; ++kk2) {
      short8 af[4], bfr[2];
#pragma unroll
      for (int m = 0; m < 4; ++m)
        af[m] = *reinterpret_cast<const short8*>(
            &al[(wr + m * 16 + r) * 64 + (((kk2 * 4 + g) ^ (r & 7)) * 8)]);
#pragma unroll
      for (int n = 0; n < 2; ++n)
        bfr[n] = *reinterpret_cast<const short8*>(
            &bl[(wc + n * 16 + r) * 64 + (((kk2 * 4 + g) ^ (r & 7)) * 8)]);
      __builtin_amdgcn_s_setprio(1);
#pragma unroll
      for (int m = 0; m < 4; ++m)
#pragma unroll
        for (int n = 0; n < 2; ++n)
          acc[m][n] = __builtin_amdgcn_mfma_f32_16x16x32_bf16(af[m], bfr[n], acc[m][n], 0, 0, 0);
      __builtin_amdgcn_s_setprio(0);
    }
  };

  STAGE_A(0, 0);  STAGE_B(0, 0);
  STAGE_A(64, 1); STAGE_B(64, 1);
  asm volatile("s_waitcnt vmcnt(6)" ::: "memory");   // tile 0 landed
  __builtin_amdgcn_s_barrier();
#pragma unroll
  for (int t = 0; t < 8; ++t) {
    __builtin_amdgcn_sched_barrier(0);
    if (t < 6) { STAGE_A((t + 2) * 64, (t + 2) % 3); STAGE_B((t + 2) * 64, (t + 2) % 3); }
    __builtin_amdgcn_sched_barrier(0);
    COMPUTE(t % 3);
    if (t < 7) {
      if (t < 6) asm volatile("s_waitcnt vmcnt(6)" ::: "memory");  // t+1 landed
      else       asm volatile("s_waitcnt vmcnt(0)" ::: "memory");
      __builtin_amdgcn_s_barrier();
    }
  }

  // ---- epilogue ----
  if (OUT_MODE == 2) {
    __syncthreads();
    unsigned short* sc = smem;   // 64 cols x 128 u16 = 16 KB
    const int wr4 = wr >> 2;     // {0, 16}
#pragma unroll
    for (int m = 0; m < 4; ++m)
#pragma unroll
      for (int n = 0; n < 2; ++n) {
        int col = wc + n * 16 + r;
        float bv = bias[bcol + col];
        int sl = wr4 + m * 4 + g;                       // local key 0..31
        int pp = ((sl >> 2) & 3) * 8 + ((sl >> 4) & 1) * 4 + (sl & 3);  // sigma
#pragma unroll
        for (int rr = 0; rr < 4; ++rr) {
          int c = (rr * 4 + (pp >> 3)) ^ (col & 7);
          sc[col * 128 + c * 8 + (pp & 7)] = f2bf((acc[m][n][rr] + bv) * scale);
        }
      }
    asm volatile("s_waitcnt lgkmcnt(0)" ::: "memory");
    __builtin_amdgcn_s_barrier();
    unsigned short* VT = (unsigned short*)Outp;
    {
      int q = tid;                    // 64 cols x 4 bb = 256 slots
      int col = q >> 2, bb = q & 3;
      int gcol = bcol + col, hh = gcol >> 6, nh = gcol & 63;
      size_t gbase = (((size_t)bb * H + hh) * NH + nh) * SL + (brow >> 2);
#pragma unroll
      for (int j = 0; j < 4; ++j) {
        short8 v = *reinterpret_cast<const short8*>(
            &sc[col * 128 + (((bb * 4 + j) ^ (col & 7)) * 8)]);
        *reinterpret_cast<short8*>(&VT[gbase + j * 8]) = v;
      }
    }
  } else {
#pragma unroll
    for (int m = 0; m < 4; ++m)
#pragma unroll
      for (int n = 0; n < 2; ++n) {
        int gcol = bcol + wc + n * 16 + r;
        float bv = bias[gcol];
#pragma unroll
        for (int rr = 0; rr < 4; ++rr) {
          int grow = brow + wr + m * 16 + g * 4 + rr;
          float val = (acc[m][n][rr] + bv) * scale;
          if (OUT_MODE == 0)
            ((float*)Outp)[(size_t)grow * D + gcol] = val;
          else
            ((unsigned short*)Outp)[(size_t)grow * D + gcol] = f2bf(val);
        }
      }
  }
}

// ---------------------------------------------------------------------------
// Flash attention v7 (unchanged): triple-buffered staging with counted
// vmcnt(8), sigma-permuted vtb, in-lane P->PV. O aliases Q.
// ---------------------------------------------------------------------------
__global__ __launch_bounds__(256, 3) void flash_attn(
    const unsigned short* __restrict__ Q, const unsigned short* __restrict__ K,
    const unsigned short* __restrict__ Vt, unsigned short* __restrict__ O) {
  __shared__ __align__(16) unsigned short k_lds[3][64 * 64];
  __shared__ __align__(16) unsigned short v_lds[3][64 * 64];

  const int bid = blockIdx.x;
  const int s = bid >> 5, idx = bid & 31;
  const int grp = idx & 7;              // XCD group
  const int bh = grp * 4 + (idx >> 3);  // 4 (b,h) per XCD group
  const int b = bh >> 3, h = bh & 7;
  const int qt = (s < 8) ? 31 - s : (s < 16) ? s + 8 : (s < 24) ? 31 - s : s - 24;
  const int q0 = qt * 64;

  const int tid = threadIdx.x;
  const int w = tid >> 6, lane = tid & 63;
  const int r = lane & 15, g = lane >> 4;
  const int swz = (r & 7) << 3;         // u16-index XOR (bits 3..5)

  const unsigned short* Qb = Q + (size_t)b * D + h * NH;
  const unsigned short* Kb = K + (size_t)b * D + h * NH;
  const unsigned short* Vb = Vt + ((size_t)(b * H + h) * NH) * SL;
  unsigned short* Ob = O + (size_t)b * D + h * NH;

  auto STAGE = [&](int kt, int bsel) {
    unsigned short* kl = &k_lds[bsel][0];
    unsigned short* vl = &v_lds[bsel][0];
#pragma unroll
    for (int j = 0; j < 2; ++j) {
      int c = j * 256 + tid;
      int row = c >> 3, c8 = (c & 7) ^ (row & 7);
      gl16(&Kb[(size_t)(kt * 64 + row) * (BS * D) + c8 * 8], &kl[c * 8]);
      gl16(&Vb[(size_t)row * SL + kt * 64 + c8 * 8], &vl[c * 8]);
    }
  };

  STAGE(0, 0);
  if (qt >= 1) STAGE(1, 1);

  short8 qf[2];
#pragma unroll
  for (int kk = 0; kk < 2; ++kk)
    qf[kk] = *reinterpret_cast<const short8*>(
        &Qb[(size_t)(q0 + w * 16 + r) * (BS * D) + kk * 32 + g * 8]);

  f32x4 oa[4];
#pragma unroll
  for (int n = 0; n < 4; ++n) oa[n] = f32x4{0.f, 0.f, 0.f, 0.f};
  float mr = -1e30f, lrp = 0.f;   // lrp: per-lane partial denominator

  int bsel = 0;
  for (int kt = 0; kt <= qt; ++kt) {
    if (kt < qt)
      asm volatile("s_waitcnt vmcnt(8)" ::: "memory");
    else
      asm volatile("s_waitcnt vmcnt(0)" ::: "memory");
    __builtin_amdgcn_s_barrier();
    __builtin_amdgcn_sched_barrier(0);
    if (kt + 2 <= qt) {
      int nb = bsel + 2; if (nb >= 3) nb -= 3;
      STAGE(kt + 2, nb);
    }

    const unsigned short* kl = &k_lds[bsel][0];
    const unsigned short* vl = &v_lds[bsel][0];
    short8 kf[2][4];
#pragma unroll
    for (int kk = 0; kk < 2; ++kk)
#pragma unroll
      for (int n = 0; n < 4; ++n)
        kf[kk][n] = *reinterpret_cast<const short8*>(
            &kl[(n * 16 + r) * 64 + ((kk * 32 + g * 8) ^ swz)]);

    f32x4 sv[4];
#pragma unroll
    for (int n = 0; n < 4; ++n) sv[n] = f32x4{0.f, 0.f, 0.f, 0.f};
#pragma unroll
    for (int kk = 0; kk < 2; ++kk)
#pragma unroll
      for (int n = 0; n < 4; ++n)
        sv[n] = __builtin_amdgcn_mfma_f32_16x16x32_bf16(kf[kk][n], qf[kk], sv[n], 0, 0, 0);

    short8 vt[2][4];
#pragma unroll
    for (int kk = 0; kk < 2; ++kk)
#pragma unroll
      for (int n = 0; n < 4; ++n)
        vt[kk][n] = *reinterpret_cast<const short8*>(
            &vl[(n * 16 + r) * 64 + ((kk * 32 + g * 8) ^ swz)]);

    if (kt == qt) {
      int qrow = q0 + w * 16 + r;
#pragma unroll
      for (int n = 0; n < 4; ++n)
#pragma unroll
        for (int rr = 0; rr < 4; ++rr)
          if (kt * 64 + n * 16 + g * 4 + rr > qrow) sv[n][rr] = -1e30f;
    }

    float t0 = fmaxf(fmaxf(sv[0][0], sv[0][1]), sv[0][2]);
    float t1 = fmaxf(fmaxf(sv[0][3], sv[1][0]), sv[1][1]);
    float t2 = fmaxf(fmaxf(sv[1][2], sv[1][3]), sv[2][0]);
    float t3 = fmaxf(fmaxf(sv[2][1], sv[2][2]), sv[2][3]);
    float t4 = fmaxf(fmaxf(sv[3][0], sv[3][1]), sv[3][2]);
    float mxl = fmaxf(fmaxf(fmaxf(t0, t1), fmaxf(t2, t3)), fmaxf(t4, sv[3][3]));
    bool need = __any(mxl > mr + 8.f);
    float mold = mr;
    float mnew = mold;
    if (need) {
      float mx = fmaxf(mxl, __shfl_xor(mxl, 16));
      mx = fmaxf(mx, __shfl_xor(mx, 32));
      mnew = fmaxf(mold, mx);
    }
#pragma unroll
    for (int n = 0; n < 4; ++n)
#pragma unroll
      for (int rr = 0; rr < 4; ++rr)
        sv[n][rr] = fast_exp2(sv[n][rr] - mnew);
    float a0 = (sv[0][0] + sv[0][1]) + (sv[0][2] + sv[0][3]);
    float a1 = (sv[1][0] + sv[1][1]) + (sv[1][2] + sv[1][3]);
    float a2 = (sv[2][0] + sv[2][1]) + (sv[2][2] + sv[2][3]);
    float a3 = (sv[3][0] + sv[3][1]) + (sv[3][2] + sv[3][3]);
    float psl = (a0 + a1) + (a2 + a3);
    if (need) {
      float sf = fast_exp2(mold - mnew);
      mr = mnew;
      lrp = lrp * sf + psl;
#pragma unroll
      for (int n = 0; n < 4; ++n) oa[n] *= sf;
    } else {
      lrp += psl;
    }

    short8 pf[2];
#pragma unroll
    for (int kk = 0; kk < 2; ++kk) {
      union { unsigned u[4]; short8 s8; } P;
      P.u[0] = cvt_pk_bf16(sv[2 * kk][0], sv[2 * kk][1]);
      P.u[1] = cvt_pk_bf16(sv[2 * kk][2], sv[2 * kk][3]);
      P.u[2] = cvt_pk_bf16(sv[2 * kk + 1][0], sv[2 * kk + 1][1]);
      P.u[3] = cvt_pk_bf16(sv[2 * kk + 1][2], sv[2 * kk + 1][3]);
      pf[kk] = P.s8;
    }

#pragma unroll
    for (int kk = 0; kk < 2; ++kk)
#pragma unroll
      for (int n = 0; n < 4; ++n)
        oa[n] = __builtin_amdgcn_mfma_f32_16x16x32_bf16(vt[kk][n], pf[kk], oa[n], 0, 0, 0);

    ++bsel; if (bsel >= 3) bsel = 0;
  }

  __syncthreads();
  {
    unsigned short* pw = &k_lds[0][0] + w * 2048;
    float lr = lrp + __shfl_xor(lrp, 16);
    lr += __shfl_xor(lr, 32);
    float inv = 1.0f / lr;
#pragma unroll
    for (int n = 0; n < 4; ++n) {
      uint2v pk;
      pk.x = cvt_pk_bf16(oa[n][0] * inv, oa[n][1] * inv);
      pk.y = cvt_pk_bf16(oa[n][2] * inv, oa[n][3] * inv);
      *reinterpret_cast<uint2v*>(&pw[r * 64 + ((n * 16 + g * 4) ^ swz)]) = pk;
    }
    asm volatile("s_waitcnt lgkmcnt(0)" ::: "memory");
    __builtin_amdgcn_sched_barrier(0);
#pragma unroll
    for (int i2 = 0; i2 < 2; ++i2) {
      int c = i2 * 64 + lane;
      int row = c >> 3, c8 = c & 7;
      short8 v = *reinterpret_cast<const short8*>(&pw[row * 64 + c8 * 8]);
      *reinterpret_cast<short8*>(
          &Ob[(size_t)(q0 + w * 16 + row) * (BS * D) + ((c8 ^ (row & 7)) * 8)]) = v;
    }
  }
}

// ---------------------------------------------------------------------------
extern "C" void kernel_launch(void* const* d_in, const int* in_sizes, int n_in,
                              void* d_out, int out_size, void* d_ws, size_t ws_size,
                              hipStream_t stream) {
  const float* x  = (const float*)d_in[0];
  const float* kx = (const float*)d_in[1];
  const float* vx = (const float*)d_in[2];
  const float* Wq = (const float*)d_in[3];
  const float* bq = (const float*)d_in[4];
  const float* Wk = (const float*)d_in[5];
  const float* bk = (const float*)d_in[6];
  const float* Wv = (const float*)d_in[7];
  const float* bv = (const float*)d_in[8];
  const float* Wo = (const float*)d_in[9];
  const float* bo = (const float*)d_in[10];

  // ws (bf16), 26 MB: qb | kb | vtb | wtb. Stream-ordered buffer reuse:
  //   conv3:  x->d_out(scratch bf16), kx->qb, vx->kb
  //   gemm_v: A=kb  -> vtb          (kb free after)
  //   gemm_k: A=qb  -> kb           (qb free after)
  //   gemm_q: A=d_out -> qb
  //   flash:  qb,kb,vtb -> qb
  //   oproj:  A=qb -> d_out (f32, overwrites scratch)
  unsigned short* ws = (unsigned short*)d_ws;
  unsigned short* qb  = ws;
  unsigned short* kb  = ws + (size_t)M_ROWS * D;
  unsigned short* vtb = ws + (size_t)M_ROWS * D * 2;
  unsigned short* wtb = ws + (size_t)M_ROWS * D * 3;
  unsigned short* xscratch = (unsigned short*)d_out;

  prep_wt<<<dim3(256), dim3(256), 0, stream>>>(Wq, Wk, Wv, Wo, wtb);
  conv3<<<dim3(2048), dim3(256), 0, stream>>>(x, kx, vx, xscratch, qb, kb);
  gemm_bf16<2><<<dim3(64, 8), dim3(256), 0, stream>>>(kb, wtb + (size_t)2 * D * D, bv, vtb, 1.0f);
  gemm_bf16<1><<<dim3(64, 8), dim3(256), 0, stream>>>(qb, wtb + (size_t)1 * D * D, bk, kb, 1.0f);
  gemm_bf16<1><<<dim3(64, 8), dim3(256), 0, stream>>>(xscratch, wtb, bq, qb, SCALE * LOG2E);
  flash_attn<<<dim3(1024), dim3(256), 0, stream>>>(qb, kb, vtb, qb);
  gemm_bf16<0><<<dim3(64, 8), dim3(256), 0, stream>>>(qb, wtb + (size_t)3 * D * D, bo, d_out, 1.0f);
}

// Round 18
// 78.427 us; speedup vs baseline: 1.1725x; 1.1725x over previous
//
#include <hip/hip_runtime.h>

typedef __attribute__((ext_vector_type(8))) short short8;
typedef __attribute__((ext_vector_type(4))) short short4v;
typedef __attribute__((ext_vector_type(4))) float f32x4;
typedef __attribute__((ext_vector_type(2))) unsigned int uint2v;

constexpr int SL = 2048, BS = 4, D = 512, H = 8, NH = 64;
constexpr int M_ROWS = SL * BS;   // 8192
constexpr float SCALE = 0.125f;   // 1/sqrt(64)
constexpr float LOG2E = 1.44269504088896340736f;

__device__ __forceinline__ unsigned short f2bf(float f) {
  union { float f; unsigned u; } v; v.f = f;
  unsigned r = v.u + 0x7FFFu + ((v.u >> 16) & 1u);
  return (unsigned short)(r >> 16);
}

__device__ __forceinline__ unsigned cvt_pk_bf16(float a, float b) {
  unsigned r;
  asm("v_cvt_pk_bf16_f32 %0, %1, %2" : "=v"(r) : "v"(a), "v"(b));
  return r;
}

__device__ __forceinline__ float fast_exp2(float x) {
  float r;
  asm("v_exp_f32 %0, %1" : "=v"(r) : "v"(x));
  return r;
}

// async global->LDS, 16B per lane; LDS dest = wave-uniform base + lane*16
__device__ __forceinline__ void gl16(const void* g, void* l) {
  __builtin_amdgcn_global_load_lds(
      (const __attribute__((address_space(1))) unsigned int*)g,
      (__attribute__((address_space(3))) unsigned int*)l, 16, 0, 0);
}

// ---------------------------------------------------------------------------
// prep: W[512][512] f32 row-major -> W^T[n][k] bf16, LDS-tiled 64x64.
// ---------------------------------------------------------------------------
__global__ __launch_bounds__(256) void prep_wt(
    const float* __restrict__ w0, const float* __restrict__ w1,
    const float* __restrict__ w2, const float* __restrict__ w3,
    unsigned short* __restrict__ wtb) {
  __shared__ float tl[64][65];
  const int tid = threadIdx.x;
  const int wi = blockIdx.x >> 6, t6 = blockIdx.x & 63;
  const int k0 = (t6 >> 3) * 64, n0 = (t6 & 7) * 64;
  const float* W = wi == 0 ? w0 : (wi == 1 ? w1 : (wi == 2 ? w2 : w3));
  unsigned short* WT = wtb + (size_t)wi * D * D;

#pragma unroll
  for (int i = 0; i < 4; ++i) {
    int k = (tid >> 4) + i * 16, n4 = (tid & 15) * 4;
    f32x4 v = *reinterpret_cast<const f32x4*>(&W[(size_t)(k0 + k) * D + n0 + n4]);
#pragma unroll
    for (int j = 0; j < 4; ++j) tl[n4 + j][k] = v[j];
  }
  __syncthreads();
#pragma unroll
  for (int i = 0; i < 2; ++i) {
    int n = (tid >> 3) + i * 32, k8 = (tid & 7) * 8;
    union { unsigned u[4]; short8 s; } pk;
#pragma unroll
    for (int j = 0; j < 4; ++j)
      pk.u[j] = cvt_pk_bf16(tl[n][k8 + 2 * j], tl[n][k8 + 2 * j + 1]);
    *reinterpret_cast<short8*>(&WT[(size_t)(n0 + n) * D + k0 + k8]) = pk.s;
  }
}

// ---------------------------------------------------------------------------
// GEMM v2: double-buffered 2-phase pipeline, counted vmcnt, XOR-swizzled LDS.
// OUT_MODE 2 (V^T) also applies the per-64-key sigma permutation
// perm5(sl) = ((sl>>2)&3)*8 + ((sl>>4)&1)*4 + (sl&3) inside the LDS bounce,
// so flash's PV B-fragment is purely in-lane with single-b128 V reads.
// ---------------------------------------------------------------------------
template <bool A_BF16, int OUT_MODE>
__device__ __forceinline__ void gemm_bt_body(const void* __restrict__ Ap,
                                             const unsigned short* __restrict__ BT,
                                             const float* __restrict__ bias,
                                             void* __restrict__ Outp, float scale,
                                             unsigned short* smem) {
  const int tid = threadIdx.x;
  const int brow = blockIdx.x * 128;
  const int bcol = blockIdx.y * 128;
  const int lane = tid & 63;
  const int wid = tid >> 6;
  const int wr = (wid >> 1) * 64;
  const int wc = (wid & 1) * 64;
  const int r = lane & 15;
  const int g = lane >> 4;

  auto a_buf = [&](int b) { return smem + b * 16384; };
  auto b_buf = [&](int b) { return smem + b * 16384 + 8192; };

  f32x4 acc[4][4];
#pragma unroll
  for (int m = 0; m < 4; ++m)
#pragma unroll
    for (int n = 0; n < 4; ++n) acc[m][n] = f32x4{0.f, 0.f, 0.f, 0.f};

  auto STAGE_B = [&](int kt, int bsel) {
    unsigned short* bl = b_buf(bsel);
#pragma unroll
    for (int j = 0; j < 4; ++j) {
      int c = j * 256 + tid;
      int row = c >> 3, c8 = (c & 7) ^ (row & 7);
      gl16(&BT[(size_t)(bcol + row) * D + kt + c8 * 8], &bl[c * 8]);
    }
  };
  auto STAGE_A_LDS = [&](int kt, int bsel) {
    const unsigned short* A = (const unsigned short*)Ap;
    unsigned short* al = a_buf(bsel);
#pragma unroll
    for (int j = 0; j < 4; ++j) {
      int c = j * 256 + tid;
      int row = c >> 3, c8 = (c & 7) ^ (row & 7);
      gl16(&A[(size_t)(brow + row) * D + kt + c8 * 8], &al[c * 8]);
    }
  };
  auto A_LOAD = [&](int kt, f32x4 (&va)[4][2]) {
    const float* A = (const float*)Ap;
#pragma unroll
    for (int j = 0; j < 4; ++j) {
      int c = j * 256 + tid;
      int row = c >> 3, c8 = (c & 7) ^ (row & 7);
      const float* ap = &A[(size_t)(brow + row) * D + kt + c8 * 8];
      va[j][0] = *reinterpret_cast<const f32x4*>(ap);
      va[j][1] = *reinterpret_cast<const f32x4*>(ap + 4);
    }
  };
  auto A_WRITE = [&](f32x4 (&va)[4][2], int bsel) {
    unsigned short* al = a_buf(bsel);
#pragma unroll
    for (int j = 0; j < 4; ++j) {
      int c = j * 256 + tid;
      union { unsigned u[4]; short8 s; } pk;
      pk.u[0] = cvt_pk_bf16(va[j][0][0], va[j][0][1]);
      pk.u[1] = cvt_pk_bf16(va[j][0][2], va[j][0][3]);
      pk.u[2] = cvt_pk_bf16(va[j][1][0], va[j][1][1]);
      pk.u[3] = cvt_pk_bf16(va[j][1][2], va[j][1][3]);
      *reinterpret_cast<short8*>(&al[c * 8]) = pk.s;
    }
  };
  auto COMPUTE = [&](int bsel) {
    const unsigned short* al = a_buf(bsel);
    const unsigned short* bl = b_buf(bsel);
#pragma unroll
    for (int kk2 = 0; kk2 < 2; ++kk2) {
      short8 af[4], bfr[4];
#pragma unroll
      for (int m = 0; m < 4; ++m)
        af[m] = *reinterpret_cast<const short8*>(
            &al[(wr + m * 16 + r) * 64 + (((kk2 * 4 + g) ^ (r & 7)) * 8)]);
#pragma unroll
      for (int n = 0; n < 4; ++n)
        bfr[n] = *reinterpret_cast<const short8*>(
            &bl[(wc + n * 16 + r) * 64 + (((kk2 * 4 + g) ^ (r & 7)) * 8)]);
      __builtin_amdgcn_s_setprio(1);
#pragma unroll
      for (int m = 0; m < 4; ++m)
#pragma unroll
        for (int n = 0; n < 4; ++n)
          acc[m][n] = __builtin_amdgcn_mfma_f32_16x16x32_bf16(af[m], bfr[n], acc[m][n], 0, 0, 0);
      __builtin_amdgcn_s_setprio(0);
    }
  };

  if (A_BF16) {
    STAGE_A_LDS(0, 0);
    STAGE_B(0, 0);
    asm volatile("s_waitcnt vmcnt(0)" ::: "memory");
  } else {
    f32x4 va[4][2];
    A_LOAD(0, va);
    STAGE_B(0, 0);
    asm volatile("s_waitcnt vmcnt(4)" ::: "memory");
    A_WRITE(va, 0);
    asm volatile("s_waitcnt vmcnt(0) lgkmcnt(0)" ::: "memory");
  }
  __builtin_amdgcn_s_barrier();

#pragma unroll
  for (int t = 0; t < 8; ++t) {
    const int cur = t & 1, nxt = cur ^ 1;
    const int ktn = (t + 1) * 64;
    __builtin_amdgcn_sched_barrier(0);
    f32x4 va[4][2];
    if (t < 7) {
      if (A_BF16) {
        STAGE_A_LDS(ktn, nxt);
        STAGE_B(ktn, nxt);
      } else {
        A_LOAD(ktn, va);
        STAGE_B(ktn, nxt);
      }
    }
    __builtin_amdgcn_sched_barrier(0);
    COMPUTE(cur);
    if (t < 7) {
      if (!A_BF16) {
        asm volatile("s_waitcnt vmcnt(2)" ::: "memory");
        A_WRITE(va, nxt);
      }
      asm volatile("s_waitcnt vmcnt(0) lgkmcnt(0)" ::: "memory");
      __builtin_amdgcn_s_barrier();
    }
  }

  if (OUT_MODE == 2) {
    unsigned short* sc = smem;
    const int wr4 = wr >> 2;
#pragma unroll
    for (int m = 0; m < 4; ++m)
#pragma unroll
      for (int n = 0; n < 4; ++n) {
        int col = wc + n * 16 + r;
        float bv = bias[bcol + col];
        int sl = wr4 + m * 4 + g;                       // local key 0..31
        int pp = ((sl >> 2) & 3) * 8 + ((sl >> 4) & 1) * 4 + (sl & 3);  // sigma
#pragma unroll
        for (int rr = 0; rr < 4; ++rr) {
          int c = (rr * 4 + (pp >> 3)) ^ (col & 7);
          sc[col * 128 + c * 8 + (pp & 7)] = f2bf((acc[m][n][rr] + bv) * scale);
        }
      }
    asm volatile("s_waitcnt lgkmcnt(0)" ::: "memory");
    __builtin_amdgcn_s_barrier();
    unsigned short* VT = (unsigned short*)Outp;
#pragma unroll
    for (int i2 = 0; i2 < 2; ++i2) {
      int q = tid * 2 + i2;
      int col = q >> 2, bb = q & 3;
      int gcol = bcol + col, hh = gcol >> 6, nh = gcol & 63;
      size_t gbase = (((size_t)bb * H + hh) * NH + nh) * SL + (brow >> 2);
#pragma unroll
      for (int j = 0; j < 4; ++j) {
        short8 v = *reinterpret_cast<const short8*>(
            &sc[col * 128 + (((bb * 4 + j) ^ (col & 7)) * 8)]);
        *reinterpret_cast<short8*>(&VT[gbase + j * 8]) = v;
      }
    }
  } else {
#pragma unroll
    for (int m = 0; m < 4; ++m)
#pragma unroll
      for (int n = 0; n < 4; ++n) {
        int gcol = bcol + wc + n * 16 + r;
        float bv = bias[gcol];
#pragma unroll
        for (int rr = 0; rr < 4; ++rr) {
          int grow = brow + wr + m * 16 + g * 4 + rr;
          float val = (acc[m][n][rr] + bv) * scale;
          if (OUT_MODE == 0)
            ((float*)Outp)[(size_t)grow * D + gcol] = val;
          else
            ((unsigned short*)Outp)[(size_t)grow * D + gcol] = f2bf(val);
        }
      }
  }
}

__global__ __launch_bounds__(256, 2) void qkv_gemm(
    const float* __restrict__ x0, const float* __restrict__ x1, const float* __restrict__ x2,
    const unsigned short* __restrict__ wtb,
    const float* __restrict__ b0, const float* __restrict__ b1, const float* __restrict__ b2,
    unsigned short* __restrict__ q_out, unsigned short* __restrict__ k_out,
    unsigned short* __restrict__ vt_out) {
  __shared__ __align__(16) unsigned short smem[2 * 16384];
  int z = blockIdx.z;
  const float* X = z == 0 ? x0 : (z == 1 ? x1 : x2);
  const unsigned short* WT = wtb + (size_t)z * D * D;
  const float* B = z == 0 ? b0 : (z == 1 ? b1 : b2);
  float scale = (z == 0) ? SCALE * LOG2E : 1.0f;
  if (z == 2)
    gemm_bt_body<false, 2>(X, WT, B, vt_out, scale, smem);
  else
    gemm_bt_body<false, 1>(X, WT, B, z == 0 ? q_out : k_out, scale, smem);
}

__global__ __launch_bounds__(256, 2) void gemm_oproj(
    const unsigned short* __restrict__ A, const unsigned short* __restrict__ WT,
    const float* __restrict__ B, float* __restrict__ Outp) {
  __shared__ __align__(16) unsigned short smem[2 * 16384];
  gemm_bt_body<true, 0>(A, WT, B, Outp, 1.0f, smem);
}

// ---------------------------------------------------------------------------
// Flash attention v7: triple-buffered staging with counted vmcnt(8) (stage
// kt+2 during phase kt; never drain to 0 mid-loop), single-b128 V reads
// (vtb sigma-permuted by the V-GEMM), in-lane P->PV. O aliases Q.
// ---------------------------------------------------------------------------
__global__ __launch_bounds__(256, 3) void flash_attn(
    const unsigned short* __restrict__ Q, const unsigned short* __restrict__ K,
    const unsigned short* __restrict__ Vt, unsigned short* __restrict__ O) {
  __shared__ __align__(16) unsigned short k_lds[3][64 * 64];
  __shared__ __align__(16) unsigned short v_lds[3][64 * 64];

  const int bid = blockIdx.x;
  const int s = bid >> 5, idx = bid & 31;
  const int grp = idx & 7;              // XCD group
  const int bh = grp * 4 + (idx >> 3);  // 4 (b,h) per XCD group
  const int b = bh >> 3, h = bh & 7;
  const int qt = (s < 8) ? 31 - s : (s < 16) ? s + 8 : (s < 24) ? 31 - s : s - 24;
  const int q0 = qt * 64;

  const int tid = threadIdx.x;
  const int w = tid >> 6, lane = tid & 63;
  const int r = lane & 15, g = lane >> 4;
  const int swz = (r & 7) << 3;         // u16-index XOR (bits 3..5)

  const unsigned short* Qb = Q + (size_t)b * D + h * NH;
  const unsigned short* Kb = K + (size_t)b * D + h * NH;
  const unsigned short* Vb = Vt + ((size_t)(b * H + h) * NH) * SL;
  unsigned short* Ob = O + (size_t)b * D + h * NH;

  auto STAGE = [&](int kt, int bsel) {
    unsigned short* kl = &k_lds[bsel][0];
    unsigned short* vl = &v_lds[bsel][0];
#pragma unroll
    for (int j = 0; j < 2; ++j) {
      int c = j * 256 + tid;
      int row = c >> 3, c8 = (c & 7) ^ (row & 7);
      gl16(&Kb[(size_t)(kt * 64 + row) * (BS * D) + c8 * 8], &kl[c * 8]);
      gl16(&Vb[(size_t)row * SL + kt * 64 + c8 * 8], &vl[c * 8]);
    }
  };

  STAGE(0, 0);
  if (qt >= 1) STAGE(1, 1);

  short8 qf[2];
#pragma unroll
  for (int kk = 0; kk < 2; ++kk)
    qf[kk] = *reinterpret_cast<const short8*>(
        &Qb[(size_t)(q0 + w * 16 + r) * (BS * D) + kk * 32 + g * 8]);

  f32x4 oa[4];
#pragma unroll
  for (int n = 0; n < 4; ++n) oa[n] = f32x4{0.f, 0.f, 0.f, 0.f};
  float mr = -1e30f, lrp = 0.f;   // lrp: per-lane partial denominator

  int bsel = 0;
  for (int kt = 0; kt <= qt; ++kt) {
    if (kt < qt)
      asm volatile("s_waitcnt vmcnt(8)" ::: "memory");
    else
      asm volatile("s_waitcnt vmcnt(0)" ::: "memory");
    __builtin_amdgcn_s_barrier();
    __builtin_amdgcn_sched_barrier(0);
    if (kt + 2 <= qt) {
      int nb = bsel + 2; if (nb >= 3) nb -= 3;
      STAGE(kt + 2, nb);
    }

    const unsigned short* kl = &k_lds[bsel][0];
    const unsigned short* vl = &v_lds[bsel][0];
    short8 kf[2][4];
#pragma unroll
    for (int kk = 0; kk < 2; ++kk)
#pragma unroll
      for (int n = 0; n < 4; ++n)
        kf[kk][n] = *reinterpret_cast<const short8*>(
            &kl[(n * 16 + r) * 64 + ((kk * 32 + g * 8) ^ swz)]);

    f32x4 sv[4];
#pragma unroll
    for (int n = 0; n < 4; ++n) sv[n] = f32x4{0.f, 0.f, 0.f, 0.f};
#pragma unroll
    for (int kk = 0; kk < 2; ++kk)
#pragma unroll
      for (int n = 0; n < 4; ++n)
        sv[n] = __builtin_amdgcn_mfma_f32_16x16x32_bf16(kf[kk][n], qf[kk], sv[n], 0, 0, 0);

    short8 vt[2][4];
#pragma unroll
    for (int kk = 0; kk < 2; ++kk)
#pragma unroll
      for (int n = 0; n < 4; ++n)
        vt[kk][n] = *reinterpret_cast<const short8*>(
            &vl[(n * 16 + r) * 64 + ((kk * 32 + g * 8) ^ swz)]);

    if (kt == qt) {
      int qrow = q0 + w * 16 + r;
#pragma unroll
      for (int n = 0; n < 4; ++n)
#pragma unroll
        for (int rr = 0; rr < 4; ++rr)
          if (kt * 64 + n * 16 + g * 4 + rr > qrow) sv[n][rr] = -1e30f;
    }

    float t0 = fmaxf(fmaxf(sv[0][0], sv[0][1]), sv[0][2]);
    float t1 = fmaxf(fmaxf(sv[0][3], sv[1][0]), sv[1][1]);
    float t2 = fmaxf(fmaxf(sv[1][2], sv[1][3]), sv[2][0]);
    float t3 = fmaxf(fmaxf(sv[2][1], sv[2][2]), sv[2][3]);
    float t4 = fmaxf(fmaxf(sv[3][0], sv[3][1]), sv[3][2]);
    float mxl = fmaxf(fmaxf(fmaxf(t0, t1), fmaxf(t2, t3)), fmaxf(t4, sv[3][3]));
    bool need = __any(mxl > mr + 8.f);
    float mold = mr;
    float mnew = mold;
    if (need) {
      float mx = fmaxf(mxl, __shfl_xor(mxl, 16));
      mx = fmaxf(mx, __shfl_xor(mx, 32));
      mnew = fmaxf(mold, mx);
    }
#pragma unroll
    for (int n = 0; n < 4; ++n)
#pragma unroll
      for (int rr = 0; rr < 4; ++rr)
        sv[n][rr] = fast_exp2(sv[n][rr] - mnew);
    float a0 = (sv[0][0] + sv[0][1]) + (sv[0][2] + sv[0][3]);
    float a1 = (sv[1][0] + sv[1][1]) + (sv[1][2] + sv[1][3]);
    float a2 = (sv[2][0] + sv[2][1]) + (sv[2][2] + sv[2][3]);
    float a3 = (sv[3][0] + sv[3][1]) + (sv[3][2] + sv[3][3]);
    float psl = (a0 + a1) + (a2 + a3);
    if (need) {
      float sf = fast_exp2(mold - mnew);
      mr = mnew;
      lrp = lrp * sf + psl;
#pragma unroll
      for (int n = 0; n < 4; ++n) oa[n] *= sf;
    } else {
      lrp += psl;
    }

    short8 pf[2];
#pragma unroll
    for (int kk = 0; kk < 2; ++kk) {
      union { unsigned u[4]; short8 s8; } P;
      P.u[0] = cvt_pk_bf16(sv[2 * kk][0], sv[2 * kk][1]);
      P.u[1] = cvt_pk_bf16(sv[2 * kk][2], sv[2 * kk][3]);
      P.u[2] = cvt_pk_bf16(sv[2 * kk + 1][0], sv[2 * kk + 1][1]);
      P.u[3] = cvt_pk_bf16(sv[2 * kk + 1][2], sv[2 * kk + 1][3]);
      pf[kk] = P.s8;
    }

#pragma unroll
    for (int kk = 0; kk < 2; ++kk)
#pragma unroll
      for (int n = 0; n < 4; ++n)
        oa[n] = __builtin_amdgcn_mfma_f32_16x16x32_bf16(vt[kk][n], pf[kk], oa[n], 0, 0, 0);

    ++bsel; if (bsel >= 3) bsel = 0;
  }

  __syncthreads();
  {
    unsigned short* pw = &k_lds[0][0] + w * 2048;
    float lr = lrp + __shfl_xor(lrp, 16);
    lr += __shfl_xor(lr, 32);
    float inv = 1.0f / lr;
#pragma unroll
    for (int n = 0; n < 4; ++n) {
      uint2v pk;
      pk.x = cvt_pk_bf16(oa[n][0] * inv, oa[n][1] * inv);
      pk.y = cvt_pk_bf16(oa[n][2] * inv, oa[n][3] * inv);
      *reinterpret_cast<uint2v*>(&pw[r * 64 + ((n * 16 + g * 4) ^ swz)]) = pk;
    }
    asm volatile("s_waitcnt lgkmcnt(0)" ::: "memory");
    __builtin_amdgcn_sched_barrier(0);
#pragma unroll
    for (int i2 = 0; i2 < 2; ++i2) {
      int c = i2 * 64 + lane;
      int row = c >> 3, c8 = c & 7;
      short8 v = *reinterpret_cast<const short8*>(&pw[row * 64 + c8 * 8]);
      *reinterpret_cast<short8*>(
          &Ob[(size_t)(q0 + w * 16 + row) * (BS * D) + ((c8 ^ (row & 7)) * 8)]) = v;
    }
  }
}

// ---------------------------------------------------------------------------
extern "C" void kernel_launch(void* const* d_in, const int* in_sizes, int n_in,
                              void* d_out, int out_size, void* d_ws, size_t ws_size,
                              hipStream_t stream) {
  const float* x  = (const float*)d_in[0];
  const float* kx = (const float*)d_in[1];
  const float* vx = (const float*)d_in[2];
  const float* Wq = (const float*)d_in[3];
  const float* bq = (const float*)d_in[4];
  const float* Wk = (const float*)d_in[5];
  const float* bk = (const float*)d_in[6];
  const float* Wv = (const float*)d_in[7];
  const float* bv = (const float*)d_in[8];
  const float* Wo = (const float*)d_in[9];
  const float* bo = (const float*)d_in[10];

  // workspace (bf16), 26 MB: qb (attn-out aliases) | kb | vtb | wtb (2 MB)
  unsigned short* ws = (unsigned short*)d_ws;
  unsigned short* qb  = ws;
  unsigned short* kb  = ws + (size_t)M_ROWS * D;
  unsigned short* vtb = ws + (size_t)M_ROWS * D * 2;
  unsigned short* wtb = ws + (size_t)M_ROWS * D * 3;

  prep_wt<<<dim3(256), dim3(256), 0, stream>>>(Wq, Wk, Wv, Wo, wtb);
  qkv_gemm<<<dim3(64, 4, 3), dim3(256), 0, stream>>>(x, kx, vx, wtb, bq, bk, bv,
                                                     qb, kb, vtb);
  flash_attn<<<dim3(1024), dim3(256), 0, stream>>>(qb, kb, vtb, qb);
  gemm_oproj<<<dim3(64, 4, 1), dim3(256), 0, stream>>>(qb, wtb + (size_t)3 * D * D,
                                                       bo, (float*)d_out);
}

// Round 19
// 77.350 us; speedup vs baseline: 1.1888x; 1.0139x over previous
//
#include <hip/hip_runtime.h>

typedef __attribute__((ext_vector_type(8))) short short8;
typedef __attribute__((ext_vector_type(4))) short short4v;
typedef __attribute__((ext_vector_type(4))) float f32x4;
typedef __attribute__((ext_vector_type(2))) unsigned int uint2v;

constexpr int SL = 2048, BS = 4, D = 512, H = 8, NH = 64;
constexpr int M_ROWS = SL * BS;   // 8192
constexpr float SCALE = 0.125f;   // 1/sqrt(64)
constexpr float LOG2E = 1.44269504088896340736f;

__device__ __forceinline__ unsigned short f2bf(float f) {
  union { float f; unsigned u; } v; v.f = f;
  unsigned r = v.u + 0x7FFFu + ((v.u >> 16) & 1u);
  return (unsigned short)(r >> 16);
}

__device__ __forceinline__ unsigned cvt_pk_bf16(float a, float b) {
  unsigned r;
  asm("v_cvt_pk_bf16_f32 %0, %1, %2" : "=v"(r) : "v"(a), "v"(b));
  return r;
}

__device__ __forceinline__ float fast_exp2(float x) {
  float r;
  asm("v_exp_f32 %0, %1" : "=v"(r) : "v"(x));
  return r;
}

// async global->LDS, 16B per lane; LDS dest = wave-uniform base + lane*16
__device__ __forceinline__ void gl16(const void* g, void* l) {
  __builtin_amdgcn_global_load_lds(
      (const __attribute__((address_space(1))) unsigned int*)g,
      (__attribute__((address_space(3))) unsigned int*)l, 16, 0, 0);
}

// ---------------------------------------------------------------------------
// prep: W[512][512] f32 row-major -> W^T[n][k] bf16, LDS-tiled 64x64.
// ---------------------------------------------------------------------------
__global__ __launch_bounds__(256) void prep_wt(
    const float* __restrict__ w0, const float* __restrict__ w1,
    const float* __restrict__ w2, const float* __restrict__ w3,
    unsigned short* __restrict__ wtb) {
  __shared__ float tl[64][65];
  const int tid = threadIdx.x;
  const int wi = blockIdx.x >> 6, t6 = blockIdx.x & 63;
  const int k0 = (t6 >> 3) * 64, n0 = (t6 & 7) * 64;
  const float* W = wi == 0 ? w0 : (wi == 1 ? w1 : (wi == 2 ? w2 : w3));
  unsigned short* WT = wtb + (size_t)wi * D * D;

#pragma unroll
  for (int i = 0; i < 4; ++i) {
    int k = (tid >> 4) + i * 16, n4 = (tid & 15) * 4;
    f32x4 v = *reinterpret_cast<const f32x4*>(&W[(size_t)(k0 + k) * D + n0 + n4]);
#pragma unroll
    for (int j = 0; j < 4; ++j) tl[n4 + j][k] = v[j];
  }
  __syncthreads();
#pragma unroll
  for (int i = 0; i < 2; ++i) {
    int n = (tid >> 3) + i * 32, k8 = (tid & 7) * 8;
    union { unsigned u[4]; short8 s; } pk;
#pragma unroll
    for (int j = 0; j < 4; ++j)
      pk.u[j] = cvt_pk_bf16(tl[n][k8 + 2 * j], tl[n][k8 + 2 * j + 1]);
    *reinterpret_cast<short8*>(&WT[(size_t)(n0 + n) * D + k0 + k8]) = pk.s;
  }
}

// ---------------------------------------------------------------------------
// GEMM v2: double-buffered 2-phase pipeline, counted vmcnt, XOR-swizzled LDS.
// Block coords are passed in (callers apply the XCD-affinity remap so the 4
// column-blocks sharing one A-row panel land on the SAME XCD -> L2 hits).
// OUT_MODE 2 (V^T) also applies the per-64-key sigma permutation.
// ---------------------------------------------------------------------------
template <bool A_BF16, int OUT_MODE>
__device__ __forceinline__ void gemm_bt_body(const void* __restrict__ Ap,
                                             const unsigned short* __restrict__ BT,
                                             const float* __restrict__ bias,
                                             void* __restrict__ Outp, float scale,
                                             unsigned short* smem,
                                             int bx, int by) {
  const int tid = threadIdx.x;
  const int brow = bx * 128;
  const int bcol = by * 128;
  const int lane = tid & 63;
  const int wid = tid >> 6;
  const int wr = (wid >> 1) * 64;
  const int wc = (wid & 1) * 64;
  const int r = lane & 15;
  const int g = lane >> 4;

  auto a_buf = [&](int b) { return smem + b * 16384; };
  auto b_buf = [&](int b) { return smem + b * 16384 + 8192; };

  f32x4 acc[4][4];
#pragma unroll
  for (int m = 0; m < 4; ++m)
#pragma unroll
    for (int n = 0; n < 4; ++n) acc[m][n] = f32x4{0.f, 0.f, 0.f, 0.f};

  auto STAGE_B = [&](int kt, int bsel) {
    unsigned short* bl = b_buf(bsel);
#pragma unroll
    for (int j = 0; j < 4; ++j) {
      int c = j * 256 + tid;
      int row = c >> 3, c8 = (c & 7) ^ (row & 7);
      gl16(&BT[(size_t)(bcol + row) * D + kt + c8 * 8], &bl[c * 8]);
    }
  };
  auto STAGE_A_LDS = [&](int kt, int bsel) {
    const unsigned short* A = (const unsigned short*)Ap;
    unsigned short* al = a_buf(bsel);
#pragma unroll
    for (int j = 0; j < 4; ++j) {
      int c = j * 256 + tid;
      int row = c >> 3, c8 = (c & 7) ^ (row & 7);
      gl16(&A[(size_t)(brow + row) * D + kt + c8 * 8], &al[c * 8]);
    }
  };
  auto A_LOAD = [&](int kt, f32x4 (&va)[4][2]) {
    const float* A = (const float*)Ap;
#pragma unroll
    for (int j = 0; j < 4; ++j) {
      int c = j * 256 + tid;
      int row = c >> 3, c8 = (c & 7) ^ (row & 7);
      const float* ap = &A[(size_t)(brow + row) * D + kt + c8 * 8];
      va[j][0] = *reinterpret_cast<const f32x4*>(ap);
      va[j][1] = *reinterpret_cast<const f32x4*>(ap + 4);
    }
  };
  auto A_WRITE = [&](f32x4 (&va)[4][2], int bsel) {
    unsigned short* al = a_buf(bsel);
#pragma unroll
    for (int j = 0; j < 4; ++j) {
      int c = j * 256 + tid;
      union { unsigned u[4]; short8 s; } pk;
      pk.u[0] = cvt_pk_bf16(va[j][0][0], va[j][0][1]);
      pk.u[1] = cvt_pk_bf16(va[j][0][2], va[j][0][3]);
      pk.u[2] = cvt_pk_bf16(va[j][1][0], va[j][1][1]);
      pk.u[3] = cvt_pk_bf16(va[j][1][2], va[j][1][3]);
      *reinterpret_cast<short8*>(&al[c * 8]) = pk.s;
    }
  };
  auto COMPUTE = [&](int bsel) {
    const unsigned short* al = a_buf(bsel);
    const unsigned short* bl = b_buf(bsel);
#pragma unroll
    for (int kk2 = 0; kk2 < 2; ++kk2) {
      short8 af[4], bfr[4];
#pragma unroll
      for (int m = 0; m < 4; ++m)
        af[m] = *reinterpret_cast<const short8*>(
            &al[(wr + m * 16 + r) * 64 + (((kk2 * 4 + g) ^ (r & 7)) * 8)]);
#pragma unroll
      for (int n = 0; n < 4; ++n)
        bfr[n] = *reinterpret_cast<const short8*>(
            &bl[(wc + n * 16 + r) * 64 + (((kk2 * 4 + g) ^ (r & 7)) * 8)]);
      __builtin_amdgcn_s_setprio(1);
#pragma unroll
      for (int m = 0; m < 4; ++m)
#pragma unroll
        for (int n = 0; n < 4; ++n)
          acc[m][n] = __builtin_amdgcn_mfma_f32_16x16x32_bf16(af[m], bfr[n], acc[m][n], 0, 0, 0);
      __builtin_amdgcn_s_setprio(0);
    }
  };

  if (A_BF16) {
    STAGE_A_LDS(0, 0);
    STAGE_B(0, 0);
    asm volatile("s_waitcnt vmcnt(0)" ::: "memory");
  } else {
    f32x4 va[4][2];
    A_LOAD(0, va);
    STAGE_B(0, 0);
    asm volatile("s_waitcnt vmcnt(4)" ::: "memory");
    A_WRITE(va, 0);
    asm volatile("s_waitcnt vmcnt(0) lgkmcnt(0)" ::: "memory");
  }
  __builtin_amdgcn_s_barrier();

#pragma unroll
  for (int t = 0; t < 8; ++t) {
    const int cur = t & 1, nxt = cur ^ 1;
    const int ktn = (t + 1) * 64;
    __builtin_amdgcn_sched_barrier(0);
    f32x4 va[4][2];
    if (t < 7) {
      if (A_BF16) {
        STAGE_A_LDS(ktn, nxt);
        STAGE_B(ktn, nxt);
      } else {
        A_LOAD(ktn, va);
        STAGE_B(ktn, nxt);
      }
    }
    __builtin_amdgcn_sched_barrier(0);
    COMPUTE(cur);
    if (t < 7) {
      if (!A_BF16) {
        asm volatile("s_waitcnt vmcnt(2)" ::: "memory");
        A_WRITE(va, nxt);
      }
      asm volatile("s_waitcnt vmcnt(0) lgkmcnt(0)" ::: "memory");
      __builtin_amdgcn_s_barrier();
    }
  }

  if (OUT_MODE == 2) {
    unsigned short* sc = smem;
    const int wr4 = wr >> 2;
#pragma unroll
    for (int m = 0; m < 4; ++m)
#pragma unroll
      for (int n = 0; n < 4; ++n) {
        int col = wc + n * 16 + r;
        float bv = bias[bcol + col];
        int sl = wr4 + m * 4 + g;                       // local key 0..31
        int pp = ((sl >> 2) & 3) * 8 + ((sl >> 4) & 1) * 4 + (sl & 3);  // sigma
#pragma unroll
        for (int rr = 0; rr < 4; ++rr) {
          int c = (rr * 4 + (pp >> 3)) ^ (col & 7);
          sc[col * 128 + c * 8 + (pp & 7)] = f2bf((acc[m][n][rr] + bv) * scale);
        }
      }
    asm volatile("s_waitcnt lgkmcnt(0)" ::: "memory");
    __builtin_amdgcn_s_barrier();
    unsigned short* VT = (unsigned short*)Outp;
#pragma unroll
    for (int i2 = 0; i2 < 2; ++i2) {
      int q = tid * 2 + i2;
      int col = q >> 2, bb = q & 3;
      int gcol = bcol + col, hh = gcol >> 6, nh = gcol & 63;
      size_t gbase = (((size_t)bb * H + hh) * NH + nh) * SL + (brow >> 2);
#pragma unroll
      for (int j = 0; j < 4; ++j) {
        short8 v = *reinterpret_cast<const short8*>(
            &sc[col * 128 + (((bb * 4 + j) ^ (col & 7)) * 8)]);
        *reinterpret_cast<short8*>(&VT[gbase + j * 8]) = v;
      }
    }
  } else {
#pragma unroll
    for (int m = 0; m < 4; ++m)
#pragma unroll
      for (int n = 0; n < 4; ++n) {
        int gcol = bcol + wc + n * 16 + r;
        float bv = bias[gcol];
#pragma unroll
        for (int rr = 0; rr < 4; ++rr) {
          int grow = brow + wr + m * 16 + g * 4 + rr;
          float val = (acc[m][n][rr] + bv) * scale;
          if (OUT_MODE == 0)
            ((float*)Outp)[(size_t)grow * D + gcol] = val;
          else
            ((unsigned short*)Outp)[(size_t)grow * D + gcol] = f2bf(val);
        }
      }
  }
}

// qkv: 1-D grid of 768. XCD-affinity decode: the 4 y-copies of an A panel
// get bids {base, base+8, base+16, base+24} -> same bid%8 -> same XCD.
__global__ __launch_bounds__(256, 2) void qkv_gemm(
    const float* __restrict__ x0, const float* __restrict__ x1, const float* __restrict__ x2,
    const unsigned short* __restrict__ wtb,
    const float* __restrict__ b0, const float* __restrict__ b1, const float* __restrict__ b2,
    unsigned short* __restrict__ q_out, unsigned short* __restrict__ k_out,
    unsigned short* __restrict__ vt_out) {
  __shared__ __align__(16) unsigned short smem[2 * 16384];
  const int bid = blockIdx.x;
  const int sgrp = bid >> 5, idx = bid & 31;
  const int xcd = idx & 7, y = idx >> 3;
  const int flat = sgrp * 8 + xcd;           // 0..191
  const int x = flat & 63, z = flat >> 6;    // z in 0..2
  const float* X = z == 0 ? x0 : (z == 1 ? x1 : x2);
  const unsigned short* WT = wtb + (size_t)z * D * D;
  const float* B = z == 0 ? b0 : (z == 1 ? b1 : b2);
  float scale = (z == 0) ? SCALE * LOG2E : 1.0f;
  if (z == 2)
    gemm_bt_body<false, 2>(X, WT, B, vt_out, scale, smem, x, y);
  else
    gemm_bt_body<false, 1>(X, WT, B, z == 0 ? q_out : k_out, scale, smem, x, y);
}

// oproj: 1-D grid of 256, same XCD-affinity decode (flat = x only).
__global__ __launch_bounds__(256, 2) void gemm_oproj(
    const unsigned short* __restrict__ A, const unsigned short* __restrict__ WT,
    const float* __restrict__ B, float* __restrict__ Outp) {
  __shared__ __align__(16) unsigned short smem[2 * 16384];
  const int bid = blockIdx.x;
  const int sgrp = bid >> 5, idx = bid & 31;
  const int xcd = idx & 7, y = idx >> 3;
  const int x = sgrp * 8 + xcd;              // 0..63
  gemm_bt_body<true, 0>(A, WT, B, Outp, 1.0f, smem, x, y);
}

// ---------------------------------------------------------------------------
// Flash attention v7 (unchanged): triple-buffered staging with counted
// vmcnt(8), sigma-permuted vtb, in-lane P->PV. O aliases Q.
// ---------------------------------------------------------------------------
__global__ __launch_bounds__(256, 3) void flash_attn(
    const unsigned short* __restrict__ Q, const unsigned short* __restrict__ K,
    const unsigned short* __restrict__ Vt, unsigned short* __restrict__ O) {
  __shared__ __align__(16) unsigned short k_lds[3][64 * 64];
  __shared__ __align__(16) unsigned short v_lds[3][64 * 64];

  const int bid = blockIdx.x;
  const int s = bid >> 5, idx = bid & 31;
  const int grp = idx & 7;              // XCD group
  const int bh = grp * 4 + (idx >> 3);  // 4 (b,h) per XCD group
  const int b = bh >> 3, h = bh & 7;
  const int qt = (s < 8) ? 31 - s : (s < 16) ? s + 8 : (s < 24) ? 31 - s : s - 24;
  const int q0 = qt * 64;

  const int tid = threadIdx.x;
  const int w = tid >> 6, lane = tid & 63;
  const int r = lane & 15, g = lane >> 4;
  const int swz = (r & 7) << 3;         // u16-index XOR (bits 3..5)

  const unsigned short* Qb = Q + (size_t)b * D + h * NH;
  const unsigned short* Kb = K + (size_t)b * D + h * NH;
  const unsigned short* Vb = Vt + ((size_t)(b * H + h) * NH) * SL;
  unsigned short* Ob = O + (size_t)b * D + h * NH;

  auto STAGE = [&](int kt, int bsel) {
    unsigned short* kl = &k_lds[bsel][0];
    unsigned short* vl = &v_lds[bsel][0];
#pragma unroll
    for (int j = 0; j < 2; ++j) {
      int c = j * 256 + tid;
      int row = c >> 3, c8 = (c & 7) ^ (row & 7);
      gl16(&Kb[(size_t)(kt * 64 + row) * (BS * D) + c8 * 8], &kl[c * 8]);
      gl16(&Vb[(size_t)row * SL + kt * 64 + c8 * 8], &vl[c * 8]);
    }
  };

  STAGE(0, 0);
  if (qt >= 1) STAGE(1, 1);

  short8 qf[2];
#pragma unroll
  for (int kk = 0; kk < 2; ++kk)
    qf[kk] = *reinterpret_cast<const short8*>(
        &Qb[(size_t)(q0 + w * 16 + r) * (BS * D) + kk * 32 + g * 8]);

  f32x4 oa[4];
#pragma unroll
  for (int n = 0; n < 4; ++n) oa[n] = f32x4{0.f, 0.f, 0.f, 0.f};
  float mr = -1e30f, lrp = 0.f;   // lrp: per-lane partial denominator

  int bsel = 0;
  for (int kt = 0; kt <= qt; ++kt) {
    if (kt < qt)
      asm volatile("s_waitcnt vmcnt(8)" ::: "memory");
    else
      asm volatile("s_waitcnt vmcnt(0)" ::: "memory");
    __builtin_amdgcn_s_barrier();
    __builtin_amdgcn_sched_barrier(0);
    if (kt + 2 <= qt) {
      int nb = bsel + 2; if (nb >= 3) nb -= 3;
      STAGE(kt + 2, nb);
    }

    const unsigned short* kl = &k_lds[bsel][0];
    const unsigned short* vl = &v_lds[bsel][0];
    short8 kf[2][4];
#pragma unroll
    for (int kk = 0; kk < 2; ++kk)
#pragma unroll
      for (int n = 0; n < 4; ++n)
        kf[kk][n] = *reinterpret_cast<const short8*>(
            &kl[(n * 16 + r) * 64 + ((kk * 32 + g * 8) ^ swz)]);

    f32x4 sv[4];
#pragma unroll
    for (int n = 0; n < 4; ++n) sv[n] = f32x4{0.f, 0.f, 0.f, 0.f};
#pragma unroll
    for (int kk = 0; kk < 2; ++kk)
#pragma unroll
      for (int n = 0; n < 4; ++n)
        sv[n] = __builtin_amdgcn_mfma_f32_16x16x32_bf16(kf[kk][n], qf[kk], sv[n], 0, 0, 0);

    short8 vt[2][4];
#pragma unroll
    for (int kk = 0; kk < 2; ++kk)
#pragma unroll
      for (int n = 0; n < 4; ++n)
        vt[kk][n] = *reinterpret_cast<const short8*>(
            &vl[(n * 16 + r) * 64 + ((kk * 32 + g * 8) ^ swz)]);

    if (kt == qt) {
      int qrow = q0 + w * 16 + r;
#pragma unroll
      for (int n = 0; n < 4; ++n)
#pragma unroll
        for (int rr = 0; rr < 4; ++rr)
          if (kt * 64 + n * 16 + g * 4 + rr > qrow) sv[n][rr] = -1e30f;
    }

    float t0 = fmaxf(fmaxf(sv[0][0], sv[0][1]), sv[0][2]);
    float t1 = fmaxf(fmaxf(sv[0][3], sv[1][0]), sv[1][1]);
    float t2 = fmaxf(fmaxf(sv[1][2], sv[1][3]), sv[2][0]);
    float t3 = fmaxf(fmaxf(sv[2][1], sv[2][2]), sv[2][3]);
    float t4 = fmaxf(fmaxf(sv[3][0], sv[3][1]), sv[3][2]);
    float mxl = fmaxf(fmaxf(fmaxf(t0, t1), fmaxf(t2, t3)), fmaxf(t4, sv[3][3]));
    bool need = __any(mxl > mr + 8.f);
    float mold = mr;
    float mnew = mold;
    if (need) {
      float mx = fmaxf(mxl, __shfl_xor(mxl, 16));
      mx = fmaxf(mx, __shfl_xor(mx, 32));
      mnew = fmaxf(mold, mx);
    }
#pragma unroll
    for (int n = 0; n < 4; ++n)
#pragma unroll
      for (int rr = 0; rr < 4; ++rr)
        sv[n][rr] = fast_exp2(sv[n][rr] - mnew);
    float a0 = (sv[0][0] + sv[0][1]) + (sv[0][2] + sv[0][3]);
    float a1 = (sv[1][0] + sv[1][1]) + (sv[1][2] + sv[1][3]);
    float a2 = (sv[2][0] + sv[2][1]) + (sv[2][2] + sv[2][3]);
    float a3 = (sv[3][0] + sv[3][1]) + (sv[3][2] + sv[3][3]);
    float psl = (a0 + a1) + (a2 + a3);
    if (need) {
      float sf = fast_exp2(mold - mnew);
      mr = mnew;
      lrp = lrp * sf + psl;
#pragma unroll
      for (int n = 0; n < 4; ++n) oa[n] *= sf;
    } else {
      lrp += psl;
    }

    short8 pf[2];
#pragma unroll
    for (int kk = 0; kk < 2; ++kk) {
      union { unsigned u[4]; short8 s8; } P;
      P.u[0] = cvt_pk_bf16(sv[2 * kk][0], sv[2 * kk][1]);
      P.u[1] = cvt_pk_bf16(sv[2 * kk][2], sv[2 * kk][3]);
      P.u[2] = cvt_pk_bf16(sv[2 * kk + 1][0], sv[2 * kk + 1][1]);
      P.u[3] = cvt_pk_bf16(sv[2 * kk + 1][2], sv[2 * kk + 1][3]);
      pf[kk] = P.s8;
    }

#pragma unroll
    for (int kk = 0; kk < 2; ++kk)
#pragma unroll
      for (int n = 0; n < 4; ++n)
        oa[n] = __builtin_amdgcn_mfma_f32_16x16x32_bf16(vt[kk][n], pf[kk], oa[n], 0, 0, 0);

    ++bsel; if (bsel >= 3) bsel = 0;
  }

  __syncthreads();
  {
    unsigned short* pw = &k_lds[0][0] + w * 2048;
    float lr = lrp + __shfl_xor(lrp, 16);
    lr += __shfl_xor(lr, 32);
    float inv = 1.0f / lr;
#pragma unroll
    for (int n = 0; n < 4; ++n) {
      uint2v pk;
      pk.x = cvt_pk_bf16(oa[n][0] * inv, oa[n][1] * inv);
      pk.y = cvt_pk_bf16(oa[n][2] * inv, oa[n][3] * inv);
      *reinterpret_cast<uint2v*>(&pw[r * 64 + ((n * 16 + g * 4) ^ swz)]) = pk;
    }
    asm volatile("s_waitcnt lgkmcnt(0)" ::: "memory");
    __builtin_amdgcn_sched_barrier(0);
#pragma unroll
    for (int i2 = 0; i2 < 2; ++i2) {
      int c = i2 * 64 + lane;
      int row = c >> 3, c8 = c & 7;
      short8 v = *reinterpret_cast<const short8*>(&pw[row * 64 + c8 * 8]);
      *reinterpret_cast<short8*>(
          &Ob[(size_t)(q0 + w * 16 + row) * (BS * D) + ((c8 ^ (row & 7)) * 8)]) = v;
    }
  }
}

// ---------------------------------------------------------------------------
extern "C" void kernel_launch(void* const* d_in, const int* in_sizes, int n_in,
                              void* d_out, int out_size, void* d_ws, size_t ws_size,
                              hipStream_t stream) {
  const float* x  = (const float*)d_in[0];
  const float* kx = (const float*)d_in[1];
  const float* vx = (const float*)d_in[2];
  const float* Wq = (const float*)d_in[3];
  const float* bq = (const float*)d_in[4];
  const float* Wk = (const float*)d_in[5];
  const float* bk = (const float*)d_in[6];
  const float* Wv = (const float*)d_in[7];
  const float* bv = (const float*)d_in[8];
  const float* Wo = (const float*)d_in[9];
  const float* bo = (const float*)d_in[10];

  // workspace (bf16), 26 MB: qb (attn-out aliases) | kb | vtb | wtb (2 MB)
  unsigned short* ws = (unsigned short*)d_ws;
  unsigned short* qb  = ws;
  unsigned short* kb  = ws + (size_t)M_ROWS * D;
  unsigned short* vtb = ws + (size_t)M_ROWS * D * 2;
  unsigned short* wtb = ws + (size_t)M_ROWS * D * 3;

  prep_wt<<<dim3(256), dim3(256), 0, stream>>>(Wq, Wk, Wv, Wo, wtb);
  qkv_gemm<<<dim3(768), dim3(256), 0, stream>>>(x, kx, vx, wtb, bq, bk, bv,
                                                qb, kb, vtb);
  flash_attn<<<dim3(1024), dim3(256), 0, stream>>>(qb, kb, vtb, qb);
  gemm_oproj<<<dim3(256), dim3(256), 0, stream>>>(qb, wtb + (size_t)3 * D * D,
                                                  bo, (float*)d_out);
}